// Round 3
// baseline (159.335 us; speedup 1.0000x reference)
//
#include <hip/hip_runtime.h>

// Problem constants (from reference setup_inputs):
//   image:  (B=4, H=512, W=640, C=16) fp32
//   depth:  (B, H, W) fp32
//   proj:   (B, 4, 4) fp32
//   out:    (B, H, W, C) fp32
constexpr int B  = 4;
constexpr int H  = 512;
constexpr int Wd = 640;
constexpr int C  = 16;                     // 4 float4 groups per pixel
constexpr int NPIX     = B * H * Wd;
constexpr int NTHREADS = NPIX * (C / 4);   // one work item per (pixel, c4)
constexpr int NHALF    = NTHREADS / 2;     // two items per thread

typedef float f32x4 __attribute__((ext_vector_type(4)));

__device__ __forceinline__ void project_one(
    int item, const float* __restrict__ depth, const float* __restrict__ proj,
    int& gi00, int& gi01, int& gi10, int& gi11,
    float& w00, float& w01, float& w10, float& w11)
{
    int c4  = item & 3;
    int pix = item >> 2;          // b*H*W + h*W + w
    int w   = pix % Wd;
    int t   = pix / Wd;
    int h   = t % H;
    int b   = t / H;

    const float* P = proj + b * 16;   // row-major 4x4
    float x = (float)w;
    float y = (float)h;
    float d = depth[pix];

    float sx = (P[0] * x + P[1] * y + P[2])  * d + P[3];
    float sy = (P[4] * x + P[5] * y + P[6])  * d + P[7];
    float sz = (P[8] * x + P[9] * y + P[10]) * d + P[11];
    float cx = sx / sz;
    float cy = sy / sz;

    float x0f = floorf(cx), y0f = floorf(cy);
    float wx1 = cx - x0f,   wy1 = cy - y0f;
    float wx0 = 1.0f - wx1, wy0 = 1.0f - wy1;
    int x0 = (int)x0f, y0 = (int)y0f;
    int x1 = x0 + 1,   y1 = y0 + 1;

    float vx0 = (x0 >= 0 && x0 < Wd) ? 1.0f : 0.0f;
    float vx1 = (x1 >= 0 && x1 < Wd) ? 1.0f : 0.0f;
    float vy0 = (y0 >= 0 && y0 < H)  ? 1.0f : 0.0f;
    float vy1 = (y1 >= 0 && y1 < H)  ? 1.0f : 0.0f;

    int x0c = min(max(x0, 0), Wd - 1);
    int x1c = min(max(x1, 0), Wd - 1);
    int y0c = min(max(y0, 0), H - 1);
    int y1c = min(max(y1, 0), H - 1);

    w00 = wy0 * wx0 * vy0 * vx0;
    w01 = wy0 * wx1 * vy0 * vx1;
    w10 = wy1 * wx0 * vy1 * vx0;
    w11 = wy1 * wx1 * vy1 * vx1;

    int base_b = b * (H * Wd * 4);    // in float4 units
    gi00 = base_b + (y0c * Wd + x0c) * 4 + c4;
    gi01 = base_b + (y0c * Wd + x1c) * 4 + c4;
    gi10 = base_b + (y1c * Wd + x0c) * 4 + c4;
    gi11 = base_b + (y1c * Wd + x1c) * 4 + c4;
}

__device__ __forceinline__ f32x4 blend(
    f32x4 g00, f32x4 g01, f32x4 g10, f32x4 g11,
    float w00, float w01, float w10, float w11)
{
    return g00 * w00 + g01 * w01 + g10 * w10 + g11 * w11;
}

__global__ __launch_bounds__(256) void depth_project_kernel(
    const float* __restrict__ image,
    const float* __restrict__ depth,
    const float* __restrict__ proj,
    f32x4* __restrict__ out)
{
    int tid = blockIdx.x * blockDim.x + threadIdx.x;
    if (tid >= NHALF) return;
    int t0 = tid;
    int t1 = tid + NHALF;

    // Two independent projection pipelines -> 8 gathers in flight.
    int ai00, ai01, ai10, ai11;  float aw00, aw01, aw10, aw11;
    int bi00, bi01, bi10, bi11;  float bw00, bw01, bw10, bw11;
    project_one(t0, depth, proj, ai00, ai01, ai10, ai11, aw00, aw01, aw10, aw11);
    project_one(t1, depth, proj, bi00, bi01, bi10, bi11, bw00, bw01, bw10, bw11);

    const f32x4* __restrict__ img4 = (const f32x4*)image;
    f32x4 a00 = img4[ai00];
    f32x4 a01 = img4[ai01];
    f32x4 a10 = img4[ai10];
    f32x4 a11 = img4[ai11];
    f32x4 b00 = img4[bi00];
    f32x4 b01 = img4[bi01];
    f32x4 b10 = img4[bi10];
    f32x4 b11 = img4[bi11];

    f32x4 r0 = blend(a00, a01, a10, a11, aw00, aw01, aw10, aw11);
    f32x4 r1 = blend(b00, b01, b10, b11, bw00, bw01, bw10, bw11);

    // Output is never re-read: bypass cache so image lines stay resident.
    __builtin_nontemporal_store(r0, &out[t0]);
    __builtin_nontemporal_store(r1, &out[t1]);
}

extern "C" void kernel_launch(void* const* d_in, const int* in_sizes, int n_in,
                              void* d_out, int out_size, void* d_ws, size_t ws_size,
                              hipStream_t stream) {
    const float* image = (const float*)d_in[0];
    const float* depth = (const float*)d_in[1];
    const float* proj  = (const float*)d_in[2];
    f32x4* out = (f32x4*)d_out;

    constexpr int block = 256;
    constexpr int grid  = (NHALF + block - 1) / block;   // 10240 blocks
    depth_project_kernel<<<grid, block, 0, stream>>>(image, depth, proj, out);
}